// Round 1
// 1837.246 us; speedup vs baseline: 1.4055x; 1.4055x over previous
//
#include <hip/hip_runtime.h>
#include <math.h>

#define N_USERS 100000
#define M_ITEMS 50000
#define N_NODES 150000
#define DIM 64
#define TIME_BINS 24
#define NNZ_CNT 4800000
#define BATCH 1024
#define NE (N_NODES * DIM)   // 9,600,000
#define NU (N_USERS * DIM)   // 6,400,000
#define NI (M_ITEMS * DIM)   // 3,200,000
#define TWO_PI 6.283185307179586f

// ---------------------------------------------------------------------------
// init: A = concat(user_emb, item_emb); ACCI = item_emb (layer-0 term)
// ---------------------------------------------------------------------------
__global__ __launch_bounds__(256) void init_kernel(
    const float* __restrict__ user_emb, const float* __restrict__ item_emb,
    float* __restrict__ A, float* __restrict__ ACCI) {
  const int nA4 = NE / 4, nI4 = NI / 4, u4 = NU / 4;
  int stride = gridDim.x * blockDim.x;
  for (int i = blockIdx.x * blockDim.x + threadIdx.x; i < nA4 + nI4; i += stride) {
    if (i < nA4) {
      float4 v = (i < u4) ? ((const float4*)user_emb)[i]
                          : ((const float4*)item_emb)[i - u4];
      ((float4*)A)[i] = v;
    } else {
      ((float4*)ACCI)[i - nA4] = ((const float4*)item_emb)[i - nA4];
    }
  }
}

__global__ __launch_bounds__(256) void zero_kernel(int* __restrict__ p, int n) {
  int stride = gridDim.x * blockDim.x;
  for (int i = blockIdx.x * blockDim.x + threadIdx.x; i < n; i += stride)
    p[i] = 0;
}

// histogram of row indices
__global__ __launch_bounds__(256) void hist_kernel(
    const int* __restrict__ rows, int* __restrict__ cnt) {
  int stride = gridDim.x * blockDim.x;
  for (int i = blockIdx.x * blockDim.x + threadIdx.x; i < NNZ_CNT; i += stride)
    atomicAdd(&cnt[rows[i]], 1);
}

// single-block exclusive scan of cnt[N_NODES] -> rp[N_NODES+1], cursor[N_NODES]
__global__ __launch_bounds__(1024) void scan_kernel(
    const int* __restrict__ cnt, int* __restrict__ rp, int* __restrict__ cursor) {
  __shared__ int part[1024];
  const int t = threadIdx.x;
  const int CH = (N_NODES + 1023) / 1024;  // 147
  int begin = t * CH;
  int endi = begin + CH;
  if (endi > N_NODES) endi = N_NODES;
  int s = 0;
  for (int i = begin; i < endi; ++i) s += cnt[i];
  part[t] = s;
  __syncthreads();
  for (int off = 1; off < 1024; off <<= 1) {
    int x = (t >= off) ? part[t - off] : 0;
    __syncthreads();
    part[t] += x;
    __syncthreads();
  }
  int run = (t == 0) ? 0 : part[t - 1];
  for (int i = begin; i < endi; ++i) {
    rp[i] = run;
    cursor[i] = run;
    run += cnt[i];
  }
  if (t == 1023) rp[N_NODES] = part[1023];
}

// scatter (col,val) pairs into row-bucketed order
__global__ __launch_bounds__(256) void scatter_kernel(
    const int* __restrict__ rows, const int* __restrict__ cols,
    const float* __restrict__ vals, int* __restrict__ cursor,
    int2* __restrict__ pairs) {
  int stride = gridDim.x * blockDim.x;
  for (int i = blockIdx.x * blockDim.x + threadIdx.x; i < NNZ_CNT; i += stride) {
    int r = rows[i];
    int pos = atomicAdd(&cursor[r], 1);
    pairs[pos] = make_int2(cols[i], __float_as_int(vals[i]));
  }
}

// ---------------------------------------------------------------------------
// CSR SpMM: one wave per row, lane = dim.
// v2: lane-cooperative pair load (1 coalesced 512B load per 64 pairs) +
// shuffle-broadcast + 8-deep unrolled gather batches -> ~8 outstanding
// gathers per wave instead of 1 chained (pairs->gather) pair.
// ---------------------------------------------------------------------------
__global__ __launch_bounds__(256) void spmm_csr_kernel(
    const float* __restrict__ ecur, float* __restrict__ enext,
    float* __restrict__ ACCI, const int* __restrict__ rp,
    const int2* __restrict__ pairs) {
  int r = blockIdx.x * 4 + (threadIdx.x >> 6);
  int lane = threadIdx.x & 63;
  if (r >= N_NODES) return;
  int start = rp[r];
  int end = rp[r + 1];
  float acc = 0.f;

  for (int jb = start; jb < end; jb += 64) {
    int n = end - jb;
    if (n > 64) n = 64;
    int jj = jb + lane;
    if (jj >= end) jj = end - 1;          // clamp: lanes >= n read a dup, unused
    int2 mp = pairs[jj];                  // one coalesced load covers the batch

    int k = 0;
    for (; k + 8 <= n; k += 8) {
      float v[8], g[8];
#pragma unroll
      for (int u = 0; u < 8; ++u) {
        int c = __shfl(mp.x, k + u);
        v[u] = __int_as_float(__shfl(mp.y, k + u));
        g[u] = ecur[c * DIM + lane];      // 8 independent gathers in flight
      }
#pragma unroll
      for (int u = 0; u < 8; ++u) acc = fmaf(v[u], g[u], acc);
    }
    if (k + 4 <= n) {
      float v[4], g[4];
#pragma unroll
      for (int u = 0; u < 4; ++u) {
        int c = __shfl(mp.x, k + u);
        v[u] = __int_as_float(__shfl(mp.y, k + u));
        g[u] = ecur[c * DIM + lane];
      }
#pragma unroll
      for (int u = 0; u < 4; ++u) acc = fmaf(v[u], g[u], acc);
      k += 4;
    }
    for (; k < n; ++k) {
      int c = __shfl(mp.x, k);
      float v = __int_as_float(__shfl(mp.y, k));
      acc = fmaf(v, ecur[c * DIM + lane], acc);
    }
  }

  enext[r * DIM + lane] = acc;
  if (r >= N_USERS) {
    int ir = r - N_USERS;
    ACCI[ir * DIM + lane] += acc;
  }
}

// gather batch-user rows of src into UACC (add=0: init, add=1: accumulate)
__global__ __launch_bounds__(256) void uacc_kernel(
    const float* __restrict__ src, const int* __restrict__ users,
    float* __restrict__ UACC, int add) {
  int idx = blockIdx.x * 256 + threadIdx.x;  // BATCH*64 total
  int b = idx >> 6, d = idx & 63;
  int u = users[b];
  float v = src[u * DIM + d];
  if (add) UACC[idx] += v; else UACC[idx] = v;
}

// ---------------------------------------------------------------------------
// clock: U2T[d][b] = 0.25*UACC[b][d]; U2T[64+d][b] = 0.5 * v_clock[b][d]
// ---------------------------------------------------------------------------
__global__ __launch_bounds__(64) void clock_kernel(
    const int* __restrict__ users, const float* __restrict__ thetas,
    const int* __restrict__ top3, const float* __restrict__ cat_emb,
    const float* __restrict__ UACC, float* __restrict__ U2T) {
  int b = blockIdx.x;
  int d = threadIdx.x;
  int u = users[b];
  float cur = thetas[b] * ((float)TIME_BINS / TWO_PI);

  float w[TIME_BINS];
  float S = 0.f;
#pragma unroll
  for (int h = 0; h < TIME_BINS; ++h) {
    float diff = fabsf(cur - (float)h);
    float delta = fminf(diff, (float)TIME_BINS - diff);
    float wh = expf(-0.5f * delta * delta);
    w[h] = wh;
    S += wh;
  }
  float inv = 1.f / (S + 1e-8f);

  float v = 0.f;
#pragma unroll
  for (int h = 0; h < TIME_BINS; ++h) {
    int base = u * (TIME_BINS * 3) + h * 3;
    int i0 = top3[base + 0];
    int i1 = top3[base + 1];
    int i2 = top3[base + 2];
    float he = (cat_emb[i0 * DIM + d] + cat_emb[i1 * DIM + d] +
                cat_emb[i2 * DIM + d]) * (1.f / 3.f);
    v += w[h] * he;
  }
  U2T[d * BATCH + b] = 0.25f * UACC[b * DIM + d];
  U2T[(DIM + d) * BATCH + b] = 0.5f * v * inv;
}

// ---------------------------------------------------------------------------
// build item matrix IT[128][M]: rows 0..63 = 0.25*ACCI^T, 64..127 = cat_emb^T
// ---------------------------------------------------------------------------
__global__ __launch_bounds__(64) void build_it_kernel(
    const float* __restrict__ ACCI, const float* __restrict__ cat_emb,
    const int* __restrict__ item_cat, float* __restrict__ IT) {
  int m = blockIdx.x * 64 + threadIdx.x;
  if (m >= M_ITEMS) return;
  int cid = item_cat[m];
#pragma unroll 4
  for (int k = 0; k < DIM; ++k) {
    IT[k * M_ITEMS + m] = 0.25f * ACCI[m * DIM + k];
    IT[(DIM + k) * M_ITEMS + m] = cat_emb[cid * DIM + k];
  }
}

// ---------------------------------------------------------------------------
// gemm: out[b][m] = sum_{k<128} U2T[k][b] * IT[k][m]
// ---------------------------------------------------------------------------
#define GK 32
#define LDP 72
__global__ __launch_bounds__(256) void gemm_kernel(
    const float* __restrict__ U2T, const float* __restrict__ IT,
    float* __restrict__ out) {
  __shared__ float sU[GK][LDP];
  __shared__ float sI[GK][LDP];
  const int m0 = blockIdx.x * 64;
  const int b0 = blockIdx.y * 64;
  const int tid = threadIdx.x;
  const int tx = tid & 15;
  const int ty = tid >> 4;
  const bool full = (m0 + 64 <= M_ITEMS);

  float acc[4][4] = {};

  for (int k0 = 0; k0 < 2 * DIM; k0 += GK) {
    int linear = tid * 8;
    int kk = linear >> 6;
    int col = linear & 63;
    {
      const float* src = &U2T[(k0 + kk) * BATCH + b0 + col];
      *(float4*)&sU[kk][col] = *(const float4*)(src);
      *(float4*)&sU[kk][col + 4] = *(const float4*)(src + 4);
    }
    if (full) {
      const float* src = &IT[(k0 + kk) * M_ITEMS + m0 + col];
      *(float4*)&sI[kk][col] = *(const float4*)(src);
      *(float4*)&sI[kk][col + 4] = *(const float4*)(src + 4);
    } else {
#pragma unroll
      for (int j = 0; j < 8; ++j) {
        int m = m0 + col + j;
        sI[kk][col + j] = (m < M_ITEMS) ? IT[(k0 + kk) * M_ITEMS + m] : 0.f;
      }
    }
    __syncthreads();

#pragma unroll
    for (int k = 0; k < GK; ++k) {
      float4 uv = *(const float4*)&sU[k][ty * 4];
      float4 iv = *(const float4*)&sI[k][tx * 4];
      float ua[4] = {uv.x, uv.y, uv.z, uv.w};
      float ia[4] = {iv.x, iv.y, iv.z, iv.w};
#pragma unroll
      for (int bi = 0; bi < 4; ++bi)
#pragma unroll
        for (int mi = 0; mi < 4; ++mi)
          acc[bi][mi] = fmaf(ua[bi], ia[mi], acc[bi][mi]);
    }
    __syncthreads();
  }

#pragma unroll
  for (int bi = 0; bi < 4; ++bi) {
    int b = b0 + ty * 4 + bi;
    int m = m0 + tx * 4;
    if (full) {
      float4 v = make_float4(acc[bi][0], acc[bi][1], acc[bi][2], acc[bi][3]);
      *(float4*)&out[b * M_ITEMS + m] = v;
    } else {
#pragma unroll
      for (int mi = 0; mi < 4; ++mi)
        if (m + mi < M_ITEMS) out[b * M_ITEMS + m + mi] = acc[bi][mi];
    }
  }
}

// ---------------------------------------------------------------------------
// launch
// ---------------------------------------------------------------------------
extern "C" void kernel_launch(void* const* d_in, const int* in_sizes, int n_in,
                              void* d_out, int out_size, void* d_ws, size_t ws_size,
                              hipStream_t stream) {
  const float* user_emb   = (const float*)d_in[0];
  const float* item_emb   = (const float*)d_in[1];
  const float* cat_emb    = (const float*)d_in[2];
  const float* graph_vals = (const float*)d_in[3];
  const int*   graph_rows = (const int*)d_in[4];
  const int*   graph_cols = (const int*)d_in[5];
  const int*   top3       = (const int*)d_in[6];
  const int*   item_cat   = (const int*)d_in[7];
  const int*   users      = (const int*)d_in[8];
  const float* thetas     = (const float*)d_in[9];
  float* out = (float*)d_out;

  // workspace layout (4-byte words):
  // A(9.6M) | B(9.6M) | pairs(9.6M) | ACCI(3.2M) | UACC(64K) | cnt | rp | cursor
  float* A      = (float*)d_ws;
  float* B      = A + NE;
  int2*  pairs  = (int2*)(B + NE);
  float* ACCI   = (float*)(pairs + NNZ_CNT);
  float* UACC   = ACCI + NI;
  int*   cnt    = (int*)(UACC + BATCH * DIM);
  int*   rp     = cnt + (N_NODES + 1);
  int*   cursor = rp + (N_NODES + 1);
  // IT / U2T alias A (dead after layer 2)
  float* IT  = A;
  float* U2T = A + 2 * DIM * M_ITEMS;  // 6.4M offset, fits in A's 9.6M

  init_kernel<<<2048, 256, 0, stream>>>(user_emb, item_emb, A, ACCI);
  zero_kernel<<<256, 256, 0, stream>>>(cnt, N_NODES + 1);
  hist_kernel<<<2048, 256, 0, stream>>>(graph_rows, cnt);
  scan_kernel<<<1, 1024, 0, stream>>>(cnt, rp, cursor);
  scatter_kernel<<<2048, 256, 0, stream>>>(graph_rows, graph_cols, graph_vals,
                                           cursor, pairs);
  uacc_kernel<<<BATCH * DIM / 256, 256, 0, stream>>>(user_emb, users, UACC, 0);

  float* cur = A;
  float* nxt = B;
  for (int l = 0; l < 3; ++l) {
    spmm_csr_kernel<<<(N_NODES + 3) / 4, 256, 0, stream>>>(cur, nxt, ACCI, rp,
                                                           pairs);
    uacc_kernel<<<BATCH * DIM / 256, 256, 0, stream>>>(nxt, users, UACC, 1);
    float* t = cur; cur = nxt; nxt = t;
  }

  clock_kernel<<<BATCH, 64, 0, stream>>>(users, thetas, top3, cat_emb, UACC, U2T);
  build_it_kernel<<<(M_ITEMS + 63) / 64, 64, 0, stream>>>(ACCI, cat_emb,
                                                          item_cat, IT);
  dim3 ggrid((M_ITEMS + 63) / 64, BATCH / 64);
  gemm_kernel<<<ggrid, 256, 0, stream>>>(U2T, IT, out);
}

// Round 2
// 1666.666 us; speedup vs baseline: 1.5494x; 1.1023x over previous
//
#include <hip/hip_runtime.h>
#include <math.h>

#define N_USERS 100000
#define M_ITEMS 50000
#define N_NODES 150000
#define DIM 64
#define TIME_BINS 24
#define NNZ_CNT 4800000
#define BATCH 1024
#define NE (N_NODES * DIM)   // 9,600,000
#define NU (N_USERS * DIM)   // 6,400,000
#define NI (M_ITEMS * DIM)   // 3,200,000
#define TWO_PI 6.283185307179586f

// bucketed scatter params
#define BSHIFT 10
#define NB ((N_NODES + (1 << BSHIFT) - 1) >> BSHIFT)  // 147
#define CHUNK 4096
#define NCHUNKS ((NNZ_CNT + CHUNK - 1) / CHUNK)       // 1172

// ---------------------------------------------------------------------------
// init: A = concat(user_emb, item_emb); ACCI = item_emb (layer-0 term)
// ---------------------------------------------------------------------------
__global__ __launch_bounds__(256) void init_kernel(
    const float* __restrict__ user_emb, const float* __restrict__ item_emb,
    float* __restrict__ A, float* __restrict__ ACCI) {
  const int nA4 = NE / 4, nI4 = NI / 4, u4 = NU / 4;
  int stride = gridDim.x * blockDim.x;
  for (int i = blockIdx.x * blockDim.x + threadIdx.x; i < nA4 + nI4; i += stride) {
    if (i < nA4) {
      float4 v = (i < u4) ? ((const float4*)user_emb)[i]
                          : ((const float4*)item_emb)[i - u4];
      ((float4*)A)[i] = v;
    } else {
      ((float4*)ACCI)[i - nA4] = ((const float4*)item_emb)[i - nA4];
    }
  }
}

__global__ __launch_bounds__(256) void zero_kernel(int* __restrict__ p, int n) {
  int stride = gridDim.x * blockDim.x;
  for (int i = blockIdx.x * blockDim.x + threadIdx.x; i < n; i += stride)
    p[i] = 0;
}

// histogram of row indices
__global__ __launch_bounds__(256) void hist_kernel(
    const int* __restrict__ rows, int* __restrict__ cnt) {
  int stride = gridDim.x * blockDim.x;
  for (int i = blockIdx.x * blockDim.x + threadIdx.x; i < NNZ_CNT; i += stride)
    atomicAdd(&cnt[rows[i]], 1);
}

// single-block exclusive scan of cnt[N_NODES] -> rp[N_NODES+1], cursor[N_NODES]
__global__ __launch_bounds__(1024) void scan_kernel(
    const int* __restrict__ cnt, int* __restrict__ rp, int* __restrict__ cursor) {
  __shared__ int part[1024];
  const int t = threadIdx.x;
  const int CH = (N_NODES + 1023) / 1024;  // 147
  int begin = t * CH;
  int endi = begin + CH;
  if (endi > N_NODES) endi = N_NODES;
  int s = 0;
  for (int i = begin; i < endi; ++i) s += cnt[i];
  part[t] = s;
  __syncthreads();
  for (int off = 1; off < 1024; off <<= 1) {
    int x = (t >= off) ? part[t - off] : 0;
    __syncthreads();
    part[t] += x;
    __syncthreads();
  }
  int run = (t == 0) ? 0 : part[t - 1];
  for (int i = begin; i < endi; ++i) {
    rp[i] = run;
    cursor[i] = run;
    run += cnt[i];
  }
  if (t == 1023) rp[N_NODES] = part[1023];
}

// init bucket cursors: bcur[b] = rp[b << BSHIFT]
__global__ __launch_bounds__(256) void binit_kernel(
    const int* __restrict__ rp, int* __restrict__ bcur) {
  int b = blockIdx.x * 256 + threadIdx.x;
  if (b < NB) bcur[b] = rp[b << BSHIFT];
}

// ---------------------------------------------------------------------------
// pass 1: bin (row,col,val) into NB row-buckets with block-local grouping so
// each bucket gets a contiguous ~28-item run per chunk (coalesced writes).
// item packed as ((row & 1023) << 18 | col, val_bits).
// ---------------------------------------------------------------------------
__global__ __launch_bounds__(256) void bucket_stage_kernel(
    const int* __restrict__ rows, const int* __restrict__ cols,
    const float* __restrict__ vals, int* __restrict__ bcur,
    int2* __restrict__ stage) {
  __shared__ int lhist[NB];
  __shared__ int loffs[NB];
  __shared__ int gbase[NB];
  __shared__ int tmp[256];
  __shared__ int2 sitems[CHUNK];
  __shared__ unsigned char sbkt[CHUNK];

  const int tid = threadIdx.x;
  const int chunk0 = blockIdx.x * CHUNK;
  int n = NNZ_CNT - chunk0;
  if (n > CHUNK) n = CHUNK;

  for (int i = tid; i < NB; i += 256) lhist[i] = 0;
  __syncthreads();

  int key[16], vbits[16], pr[16];
#pragma unroll
  for (int u = 0; u < 16; ++u) {
    int li = u * 256 + tid;
    if (li < n) {
      int i = chunk0 + li;
      int r = rows[i];
      int c = cols[i];
      float v = vals[i];
      int b = r >> BSHIFT;
      int rank = atomicAdd(&lhist[b], 1);
      key[u] = ((r & ((1 << BSHIFT) - 1)) << 18) | c;
      vbits[u] = __float_as_int(v);
      pr[u] = (b << 12) | rank;
    } else {
      pr[u] = -1;
    }
  }
  __syncthreads();

  // inclusive scan over NB (padded to 256)
  int x = (tid < NB) ? lhist[tid] : 0;
  tmp[tid] = x;
  __syncthreads();
  for (int off = 1; off < 256; off <<= 1) {
    int y = (tid >= off) ? tmp[tid - off] : 0;
    __syncthreads();
    tmp[tid] += y;
    __syncthreads();
  }
  if (tid < NB) {
    loffs[tid] = tmp[tid] - x;  // exclusive offset
    gbase[tid] = (x > 0) ? atomicAdd(&bcur[tid], x) : 0;
  }
  __syncthreads();

  // scatter to LDS grouped by bucket
#pragma unroll
  for (int u = 0; u < 16; ++u) {
    if (pr[u] >= 0) {
      int b = pr[u] >> 12;
      int rank = pr[u] & 4095;
      int p = loffs[b] + rank;
      sitems[p] = make_int2(key[u], vbits[u]);
      sbkt[p] = (unsigned char)b;
    }
  }
  __syncthreads();

  // coalesced run writes to global bucket windows
  for (int j = tid; j < n; j += 256) {
    int b = sbkt[j];
    int2 it = sitems[j];
    stage[gbase[b] + (j - loffs[b])] = it;
  }
}

// ---------------------------------------------------------------------------
// pass 2: one block per bucket. Random writes confined to this bucket's
// ~260KB pairs window -> lines complete inside one L2 before eviction.
// ---------------------------------------------------------------------------
__global__ __launch_bounds__(512) void bucket_scatter_kernel(
    const int2* __restrict__ stage, const int* __restrict__ rp,
    int* __restrict__ cursor, int2* __restrict__ pairs) {
  const int b = blockIdx.x;
  const int rbase = b << BSHIFT;
  int rend = rbase + (1 << BSHIFT);
  if (rend > N_NODES) rend = N_NODES;
  const int wstart = rp[rbase];
  const int wend = rp[rend];
  for (int j = wstart + threadIdx.x; j < wend; j += 512) {
    int2 it = stage[j];
    int r = rbase + (it.x >> 18);
    int c = it.x & 0x3FFFF;
    int pos = atomicAdd(&cursor[r], 1);
    pairs[pos] = make_int2(c, it.y);
  }
}

// ---------------------------------------------------------------------------
// CSR SpMM: one wave per row, lane = dim. Lane-cooperative pair load +
// shuffle-broadcast + 8-deep unrolled gather batches.
// ---------------------------------------------------------------------------
__global__ __launch_bounds__(256) void spmm_csr_kernel(
    const float* __restrict__ ecur, float* __restrict__ enext,
    float* __restrict__ ACCI, const int* __restrict__ rp,
    const int2* __restrict__ pairs) {
  int r = blockIdx.x * 4 + (threadIdx.x >> 6);
  int lane = threadIdx.x & 63;
  if (r >= N_NODES) return;
  int start = rp[r];
  int end = rp[r + 1];
  float acc = 0.f;

  for (int jb = start; jb < end; jb += 64) {
    int n = end - jb;
    if (n > 64) n = 64;
    int jj = jb + lane;
    if (jj >= end) jj = end - 1;          // clamp: lanes >= n read a dup, unused
    int2 mp = pairs[jj];                  // one coalesced load covers the batch

    int k = 0;
    for (; k + 8 <= n; k += 8) {
      float v[8], g[8];
#pragma unroll
      for (int u = 0; u < 8; ++u) {
        int c = __shfl(mp.x, k + u);
        v[u] = __int_as_float(__shfl(mp.y, k + u));
        g[u] = ecur[c * DIM + lane];      // 8 independent gathers in flight
      }
#pragma unroll
      for (int u = 0; u < 8; ++u) acc = fmaf(v[u], g[u], acc);
    }
    if (k + 4 <= n) {
      float v[4], g[4];
#pragma unroll
      for (int u = 0; u < 4; ++u) {
        int c = __shfl(mp.x, k + u);
        v[u] = __int_as_float(__shfl(mp.y, k + u));
        g[u] = ecur[c * DIM + lane];
      }
#pragma unroll
      for (int u = 0; u < 4; ++u) acc = fmaf(v[u], g[u], acc);
      k += 4;
    }
    for (; k < n; ++k) {
      int c = __shfl(mp.x, k);
      float v = __int_as_float(__shfl(mp.y, k));
      acc = fmaf(v, ecur[c * DIM + lane], acc);
    }
  }

  enext[r * DIM + lane] = acc;
  if (r >= N_USERS) {
    int ir = r - N_USERS;
    ACCI[ir * DIM + lane] += acc;
  }
}

// gather batch-user rows of src into UACC (add=0: init, add=1: accumulate)
__global__ __launch_bounds__(256) void uacc_kernel(
    const float* __restrict__ src, const int* __restrict__ users,
    float* __restrict__ UACC, int add) {
  int idx = blockIdx.x * 256 + threadIdx.x;  // BATCH*64 total
  int b = idx >> 6, d = idx & 63;
  int u = users[b];
  float v = src[u * DIM + d];
  if (add) UACC[idx] += v; else UACC[idx] = v;
}

// ---------------------------------------------------------------------------
// clock: U2T[d][b] = 0.25*UACC[b][d]; U2T[64+d][b] = 0.5 * v_clock[b][d]
// ---------------------------------------------------------------------------
__global__ __launch_bounds__(64) void clock_kernel(
    const int* __restrict__ users, const float* __restrict__ thetas,
    const int* __restrict__ top3, const float* __restrict__ cat_emb,
    const float* __restrict__ UACC, float* __restrict__ U2T) {
  int b = blockIdx.x;
  int d = threadIdx.x;
  int u = users[b];
  float cur = thetas[b] * ((float)TIME_BINS / TWO_PI);

  float w[TIME_BINS];
  float S = 0.f;
#pragma unroll
  for (int h = 0; h < TIME_BINS; ++h) {
    float diff = fabsf(cur - (float)h);
    float delta = fminf(diff, (float)TIME_BINS - diff);
    float wh = expf(-0.5f * delta * delta);
    w[h] = wh;
    S += wh;
  }
  float inv = 1.f / (S + 1e-8f);

  float v = 0.f;
#pragma unroll
  for (int h = 0; h < TIME_BINS; ++h) {
    int base = u * (TIME_BINS * 3) + h * 3;
    int i0 = top3[base + 0];
    int i1 = top3[base + 1];
    int i2 = top3[base + 2];
    float he = (cat_emb[i0 * DIM + d] + cat_emb[i1 * DIM + d] +
                cat_emb[i2 * DIM + d]) * (1.f / 3.f);
    v += w[h] * he;
  }
  U2T[d * BATCH + b] = 0.25f * UACC[b * DIM + d];
  U2T[(DIM + d) * BATCH + b] = 0.5f * v * inv;
}

// ---------------------------------------------------------------------------
// build item matrix IT[128][M]: rows 0..63 = 0.25*ACCI^T, 64..127 = cat_emb^T
// ---------------------------------------------------------------------------
__global__ __launch_bounds__(64) void build_it_kernel(
    const float* __restrict__ ACCI, const float* __restrict__ cat_emb,
    const int* __restrict__ item_cat, float* __restrict__ IT) {
  int m = blockIdx.x * 64 + threadIdx.x;
  if (m >= M_ITEMS) return;
  int cid = item_cat[m];
#pragma unroll 4
  for (int k = 0; k < DIM; ++k) {
    IT[k * M_ITEMS + m] = 0.25f * ACCI[m * DIM + k];
    IT[(DIM + k) * M_ITEMS + m] = cat_emb[cid * DIM + k];
  }
}

// ---------------------------------------------------------------------------
// gemm: out[b][m] = sum_{k<128} U2T[k][b] * IT[k][m]
// ---------------------------------------------------------------------------
#define GK 32
#define LDP 72
__global__ __launch_bounds__(256) void gemm_kernel(
    const float* __restrict__ U2T, const float* __restrict__ IT,
    float* __restrict__ out) {
  __shared__ float sU[GK][LDP];
  __shared__ float sI[GK][LDP];
  const int m0 = blockIdx.x * 64;
  const int b0 = blockIdx.y * 64;
  const int tid = threadIdx.x;
  const int tx = tid & 15;
  const int ty = tid >> 4;
  const bool full = (m0 + 64 <= M_ITEMS);

  float acc[4][4] = {};

  for (int k0 = 0; k0 < 2 * DIM; k0 += GK) {
    int linear = tid * 8;
    int kk = linear >> 6;
    int col = linear & 63;
    {
      const float* src = &U2T[(k0 + kk) * BATCH + b0 + col];
      *(float4*)&sU[kk][col] = *(const float4*)(src);
      *(float4*)&sU[kk][col + 4] = *(const float4*)(src + 4);
    }
    if (full) {
      const float* src = &IT[(k0 + kk) * M_ITEMS + m0 + col];
      *(float4*)&sI[kk][col] = *(const float4*)(src);
      *(float4*)&sI[kk][col + 4] = *(const float4*)(src + 4);
    } else {
#pragma unroll
      for (int j = 0; j < 8; ++j) {
        int m = m0 + col + j;
        sI[kk][col + j] = (m < M_ITEMS) ? IT[(k0 + kk) * M_ITEMS + m] : 0.f;
      }
    }
    __syncthreads();

#pragma unroll
    for (int k = 0; k < GK; ++k) {
      float4 uv = *(const float4*)&sU[k][ty * 4];
      float4 iv = *(const float4*)&sI[k][tx * 4];
      float ua[4] = {uv.x, uv.y, uv.z, uv.w};
      float ia[4] = {iv.x, iv.y, iv.z, iv.w};
#pragma unroll
      for (int bi = 0; bi < 4; ++bi)
#pragma unroll
        for (int mi = 0; mi < 4; ++mi)
          acc[bi][mi] = fmaf(ua[bi], ia[mi], acc[bi][mi]);
    }
    __syncthreads();
  }

#pragma unroll
  for (int bi = 0; bi < 4; ++bi) {
    int b = b0 + ty * 4 + bi;
    int m = m0 + tx * 4;
    if (full) {
      float4 v = make_float4(acc[bi][0], acc[bi][1], acc[bi][2], acc[bi][3]);
      *(float4*)&out[b * M_ITEMS + m] = v;
    } else {
#pragma unroll
      for (int mi = 0; mi < 4; ++mi)
        if (m + mi < M_ITEMS) out[b * M_ITEMS + m + mi] = acc[bi][mi];
    }
  }
}

// ---------------------------------------------------------------------------
// launch
// ---------------------------------------------------------------------------
extern "C" void kernel_launch(void* const* d_in, const int* in_sizes, int n_in,
                              void* d_out, int out_size, void* d_ws, size_t ws_size,
                              hipStream_t stream) {
  const float* user_emb   = (const float*)d_in[0];
  const float* item_emb   = (const float*)d_in[1];
  const float* cat_emb    = (const float*)d_in[2];
  const float* graph_vals = (const float*)d_in[3];
  const int*   graph_rows = (const int*)d_in[4];
  const int*   graph_cols = (const int*)d_in[5];
  const int*   top3       = (const int*)d_in[6];
  const int*   item_cat   = (const int*)d_in[7];
  const int*   users      = (const int*)d_in[8];
  const float* thetas     = (const float*)d_in[9];
  float* out = (float*)d_out;

  // workspace layout (4-byte words):
  // A(9.6M) | B(9.6M) | pairs(9.6M) | ACCI(3.2M) | UACC(64K) | cnt | rp | cursor | bcur
  float* A      = (float*)d_ws;
  float* B      = A + NE;
  int2*  pairs  = (int2*)(B + NE);
  float* ACCI   = (float*)(pairs + NNZ_CNT);
  float* UACC   = ACCI + NI;
  int*   cnt    = (int*)(UACC + BATCH * DIM);
  int*   rp     = cnt + (N_NODES + 1);
  int*   cursor = rp + (N_NODES + 1);
  int*   bcur   = cursor + N_NODES;
  // stage aliases B (dead until first spmm writes it)
  int2* stage = (int2*)B;
  // IT / U2T alias A (dead after layer 2)
  float* IT  = A;
  float* U2T = A + 2 * DIM * M_ITEMS;  // 6.4M offset, fits in A's 9.6M

  init_kernel<<<2048, 256, 0, stream>>>(user_emb, item_emb, A, ACCI);
  zero_kernel<<<256, 256, 0, stream>>>(cnt, N_NODES + 1);
  hist_kernel<<<2048, 256, 0, stream>>>(graph_rows, cnt);
  scan_kernel<<<1, 1024, 0, stream>>>(cnt, rp, cursor);
  binit_kernel<<<1, 256, 0, stream>>>(rp, bcur);
  bucket_stage_kernel<<<NCHUNKS, 256, 0, stream>>>(graph_rows, graph_cols,
                                                   graph_vals, bcur, stage);
  bucket_scatter_kernel<<<NB, 512, 0, stream>>>(stage, rp, cursor, pairs);
  uacc_kernel<<<BATCH * DIM / 256, 256, 0, stream>>>(user_emb, users, UACC, 0);

  float* cur = A;
  float* nxt = B;
  for (int l = 0; l < 3; ++l) {
    spmm_csr_kernel<<<(N_NODES + 3) / 4, 256, 0, stream>>>(cur, nxt, ACCI, rp,
                                                           pairs);
    uacc_kernel<<<BATCH * DIM / 256, 256, 0, stream>>>(nxt, users, UACC, 1);
    float* t = cur; cur = nxt; nxt = t;
  }

  clock_kernel<<<BATCH, 64, 0, stream>>>(users, thetas, top3, cat_emb, UACC, U2T);
  build_it_kernel<<<(M_ITEMS + 63) / 64, 64, 0, stream>>>(ACCI, cat_emb,
                                                          item_cat, IT);
  dim3 ggrid((M_ITEMS + 63) / 64, BATCH / 64);
  gemm_kernel<<<ggrid, 256, 0, stream>>>(U2T, IT, out);
}

// Round 3
// 1354.482 us; speedup vs baseline: 1.9065x; 1.2305x over previous
//
#include <hip/hip_runtime.h>
#include <math.h>

#define N_USERS 100000
#define M_ITEMS 50000
#define N_NODES 150000
#define DIM 64
#define TIME_BINS 24
#define NNZ_CNT 4800000
#define BATCH 1024
#define NE (N_NODES * DIM)   // 9,600,000
#define NU (N_USERS * DIM)   // 6,400,000
#define NI (M_ITEMS * DIM)   // 3,200,000
#define TWO_PI 6.283185307179586f

// bucketed scatter params
#define BSHIFT 10
#define NB ((N_NODES + (1 << BSHIFT) - 1) >> BSHIFT)  // 147
#define CHUNK 4096
#define NCHUNKS ((NNZ_CNT + CHUNK - 1) / CHUNK)       // 1172

// multi-block scan params
#define SCB 1024
#define NSB ((N_NODES + SCB - 1) / SCB)               // 147

// ---------------------------------------------------------------------------
// init: A = concat(user_emb, item_emb); ACCI = item_emb (layer-0 term)
// ---------------------------------------------------------------------------
__global__ __launch_bounds__(256) void init_kernel(
    const float* __restrict__ user_emb, const float* __restrict__ item_emb,
    float* __restrict__ A, float* __restrict__ ACCI) {
  const int nA4 = NE / 4, nI4 = NI / 4, u4 = NU / 4;
  int stride = gridDim.x * blockDim.x;
  for (int i = blockIdx.x * blockDim.x + threadIdx.x; i < nA4 + nI4; i += stride) {
    if (i < nA4) {
      float4 v = (i < u4) ? ((const float4*)user_emb)[i]
                          : ((const float4*)item_emb)[i - u4];
      ((float4*)A)[i] = v;
    } else {
      ((float4*)ACCI)[i - nA4] = ((const float4*)item_emb)[i - nA4];
    }
  }
}

__global__ __launch_bounds__(256) void zero_kernel(int* __restrict__ p, int n) {
  int stride = gridDim.x * blockDim.x;
  for (int i = blockIdx.x * blockDim.x + threadIdx.x; i < n; i += stride)
    p[i] = 0;
}

// histogram of row indices
__global__ __launch_bounds__(256) void hist_kernel(
    const int* __restrict__ rows, int* __restrict__ cnt) {
  int stride = gridDim.x * blockDim.x;
  for (int i = blockIdx.x * blockDim.x + threadIdx.x; i < NNZ_CNT; i += stride)
    atomicAdd(&cnt[rows[i]], 1);
}

// ---------------------------------------------------------------------------
// device-wide exclusive scan of cnt[N_NODES] -> rp/cursor, in 3 phases
// ---------------------------------------------------------------------------
// phase 1: per-block sums
__global__ __launch_bounds__(SCB) void scan_sums_kernel(
    const int* __restrict__ cnt, int* __restrict__ bsum) {
  int i = blockIdx.x * SCB + threadIdx.x;
  int x = (i < N_NODES) ? cnt[i] : 0;
#pragma unroll
  for (int off = 1; off < 64; off <<= 1) x += __shfl_xor(x, off);
  __shared__ int ws[SCB / 64];
  int wid = threadIdx.x >> 6, lane = threadIdx.x & 63;
  if (lane == 0) ws[wid] = x;
  __syncthreads();
  if (threadIdx.x == 0) {
    int s = 0;
#pragma unroll
    for (int w = 0; w < SCB / 64; ++w) s += ws[w];
    bsum[blockIdx.x] = s;
  }
}

// phase 2: scan the NSB block sums (1 block), also write rp[N_NODES]=total
__global__ __launch_bounds__(256) void scan_offsets_kernel(
    const int* __restrict__ bsum, int* __restrict__ boff, int* __restrict__ rp) {
  __shared__ int tmp[256];
  int t = threadIdx.x;
  int x = (t < NSB) ? bsum[t] : 0;
  tmp[t] = x;
  __syncthreads();
  for (int off = 1; off < 256; off <<= 1) {
    int y = (t >= off) ? tmp[t - off] : 0;
    __syncthreads();
    tmp[t] += y;
    __syncthreads();
  }
  if (t < NSB) boff[t] = tmp[t] - x;
  if (t == 255) rp[N_NODES] = tmp[255];
}

// phase 3: per-block exclusive scan + block offset -> rp, cursor
__global__ __launch_bounds__(SCB) void scan_write_kernel(
    const int* __restrict__ cnt, const int* __restrict__ boff,
    int* __restrict__ rp, int* __restrict__ cursor) {
  int i = blockIdx.x * SCB + threadIdx.x;
  int x = (i < N_NODES) ? cnt[i] : 0;
  int lane = threadIdx.x & 63, wid = threadIdx.x >> 6;
  int inc = x;
#pragma unroll
  for (int off = 1; off < 64; off <<= 1) {
    int y = __shfl_up(inc, off);
    if (lane >= off) inc += y;
  }
  __shared__ int ws[SCB / 64];
  if (lane == 63) ws[wid] = inc;
  __syncthreads();
  int wofs = 0;
  for (int w = 0; w < wid; ++w) wofs += ws[w];
  int excl = boff[blockIdx.x] + wofs + inc - x;
  if (i < N_NODES) {
    rp[i] = excl;
    cursor[i] = excl;
  }
}

// init bucket cursors: bcur[b] = rp[b << BSHIFT]
__global__ __launch_bounds__(256) void binit_kernel(
    const int* __restrict__ rp, int* __restrict__ bcur) {
  int b = blockIdx.x * 256 + threadIdx.x;
  if (b < NB) bcur[b] = rp[b << BSHIFT];
}

// ---------------------------------------------------------------------------
// pass 1: bin (row,col,val) into NB row-buckets with block-local grouping so
// each bucket gets a contiguous ~28-item run per chunk (coalesced writes).
// item packed as ((row & 1023) << 18 | col, val_bits).
// ---------------------------------------------------------------------------
__global__ __launch_bounds__(256) void bucket_stage_kernel(
    const int* __restrict__ rows, const int* __restrict__ cols,
    const float* __restrict__ vals, int* __restrict__ bcur,
    int2* __restrict__ stage) {
  __shared__ int lhist[NB];
  __shared__ int loffs[NB];
  __shared__ int gbase[NB];
  __shared__ int tmp[256];
  __shared__ int2 sitems[CHUNK];
  __shared__ unsigned char sbkt[CHUNK];

  const int tid = threadIdx.x;
  const int chunk0 = blockIdx.x * CHUNK;
  int n = NNZ_CNT - chunk0;
  if (n > CHUNK) n = CHUNK;

  for (int i = tid; i < NB; i += 256) lhist[i] = 0;
  __syncthreads();

  int key[16], vbits[16], pr[16];
#pragma unroll
  for (int u = 0; u < 16; ++u) {
    int li = u * 256 + tid;
    if (li < n) {
      int i = chunk0 + li;
      int r = rows[i];
      int c = cols[i];
      float v = vals[i];
      int b = r >> BSHIFT;
      int rank = atomicAdd(&lhist[b], 1);
      key[u] = ((r & ((1 << BSHIFT) - 1)) << 18) | c;
      vbits[u] = __float_as_int(v);
      pr[u] = (b << 12) | rank;
    } else {
      pr[u] = -1;
    }
  }
  __syncthreads();

  // inclusive scan over NB (padded to 256)
  int x = (tid < NB) ? lhist[tid] : 0;
  tmp[tid] = x;
  __syncthreads();
  for (int off = 1; off < 256; off <<= 1) {
    int y = (tid >= off) ? tmp[tid - off] : 0;
    __syncthreads();
    tmp[tid] += y;
    __syncthreads();
  }
  if (tid < NB) {
    loffs[tid] = tmp[tid] - x;  // exclusive offset
    gbase[tid] = (x > 0) ? atomicAdd(&bcur[tid], x) : 0;
  }
  __syncthreads();

  // scatter to LDS grouped by bucket
#pragma unroll
  for (int u = 0; u < 16; ++u) {
    if (pr[u] >= 0) {
      int b = pr[u] >> 12;
      int rank = pr[u] & 4095;
      int p = loffs[b] + rank;
      sitems[p] = make_int2(key[u], vbits[u]);
      sbkt[p] = (unsigned char)b;
    }
  }
  __syncthreads();

  // coalesced run writes to global bucket windows
  for (int j = tid; j < n; j += 256) {
    int b = sbkt[j];
    int2 it = sitems[j];
    stage[gbase[b] + (j - loffs[b])] = it;
  }
}

// ---------------------------------------------------------------------------
// pass 2: one block per bucket. Random writes confined to this bucket's
// ~260KB pairs window -> lines complete inside one L2 before eviction.
// ---------------------------------------------------------------------------
__global__ __launch_bounds__(512) void bucket_scatter_kernel(
    const int2* __restrict__ stage, const int* __restrict__ rp,
    int* __restrict__ cursor, int2* __restrict__ pairs) {
  const int b = blockIdx.x;
  const int rbase = b << BSHIFT;
  int rend = rbase + (1 << BSHIFT);
  if (rend > N_NODES) rend = N_NODES;
  const int wstart = rp[rbase];
  const int wend = rp[rend];
  for (int j = wstart + threadIdx.x; j < wend; j += 512) {
    int2 it = stage[j];
    int r = rbase + (it.x >> 18);
    int c = it.x & 0x3FFFF;
    int pos = atomicAdd(&cursor[r], 1);
    pairs[pos] = make_int2(c, it.y);
  }
}

// ---------------------------------------------------------------------------
// CSR SpMM: one wave per row, lane = dim. Lane-cooperative pair load +
// shuffle-broadcast + 8-deep unrolled gather batches.
// ---------------------------------------------------------------------------
__global__ __launch_bounds__(256) void spmm_csr_kernel(
    const float* __restrict__ ecur, float* __restrict__ enext,
    float* __restrict__ ACCI, const int* __restrict__ rp,
    const int2* __restrict__ pairs) {
  int r = blockIdx.x * 4 + (threadIdx.x >> 6);
  int lane = threadIdx.x & 63;
  if (r >= N_NODES) return;
  int start = rp[r];
  int end = rp[r + 1];
  float acc = 0.f;

  for (int jb = start; jb < end; jb += 64) {
    int n = end - jb;
    if (n > 64) n = 64;
    int jj = jb + lane;
    if (jj >= end) jj = end - 1;          // clamp: lanes >= n read a dup, unused
    int2 mp = pairs[jj];                  // one coalesced load covers the batch

    int k = 0;
    for (; k + 8 <= n; k += 8) {
      float v[8], g[8];
#pragma unroll
      for (int u = 0; u < 8; ++u) {
        int c = __shfl(mp.x, k + u);
        v[u] = __int_as_float(__shfl(mp.y, k + u));
        g[u] = ecur[c * DIM + lane];      // 8 independent gathers in flight
      }
#pragma unroll
      for (int u = 0; u < 8; ++u) acc = fmaf(v[u], g[u], acc);
    }
    if (k + 4 <= n) {
      float v[4], g[4];
#pragma unroll
      for (int u = 0; u < 4; ++u) {
        int c = __shfl(mp.x, k + u);
        v[u] = __int_as_float(__shfl(mp.y, k + u));
        g[u] = ecur[c * DIM + lane];
      }
#pragma unroll
      for (int u = 0; u < 4; ++u) acc = fmaf(v[u], g[u], acc);
      k += 4;
    }
    for (; k < n; ++k) {
      int c = __shfl(mp.x, k);
      float v = __int_as_float(__shfl(mp.y, k));
      acc = fmaf(v, ecur[c * DIM + lane], acc);
    }
  }

  enext[r * DIM + lane] = acc;
  if (r >= N_USERS) {
    int ir = r - N_USERS;
    ACCI[ir * DIM + lane] += acc;
  }
}

// gather batch-user rows of src into UACC (add=0: init, add=1: accumulate)
__global__ __launch_bounds__(256) void uacc_kernel(
    const float* __restrict__ src, const int* __restrict__ users,
    float* __restrict__ UACC, int add) {
  int idx = blockIdx.x * 256 + threadIdx.x;  // BATCH*64 total
  int b = idx >> 6, d = idx & 63;
  int u = users[b];
  float v = src[u * DIM + d];
  if (add) UACC[idx] += v; else UACC[idx] = v;
}

// ---------------------------------------------------------------------------
// clock: U2T[d][b] = 0.25*UACC[b][d]; U2T[64+d][b] = 0.5 * v_clock[b][d]
// ---------------------------------------------------------------------------
__global__ __launch_bounds__(64) void clock_kernel(
    const int* __restrict__ users, const float* __restrict__ thetas,
    const int* __restrict__ top3, const float* __restrict__ cat_emb,
    const float* __restrict__ UACC, float* __restrict__ U2T) {
  int b = blockIdx.x;
  int d = threadIdx.x;
  int u = users[b];
  float cur = thetas[b] * ((float)TIME_BINS / TWO_PI);

  float w[TIME_BINS];
  float S = 0.f;
#pragma unroll
  for (int h = 0; h < TIME_BINS; ++h) {
    float diff = fabsf(cur - (float)h);
    float delta = fminf(diff, (float)TIME_BINS - diff);
    float wh = expf(-0.5f * delta * delta);
    w[h] = wh;
    S += wh;
  }
  float inv = 1.f / (S + 1e-8f);

  float v = 0.f;
#pragma unroll
  for (int h = 0; h < TIME_BINS; ++h) {
    int base = u * (TIME_BINS * 3) + h * 3;
    int i0 = top3[base + 0];
    int i1 = top3[base + 1];
    int i2 = top3[base + 2];
    float he = (cat_emb[i0 * DIM + d] + cat_emb[i1 * DIM + d] +
                cat_emb[i2 * DIM + d]) * (1.f / 3.f);
    v += w[h] * he;
  }
  U2T[d * BATCH + b] = 0.25f * UACC[b * DIM + d];
  U2T[(DIM + d) * BATCH + b] = 0.5f * v * inv;
}

// ---------------------------------------------------------------------------
// build item matrix IT[128][M]: rows 0..63 = 0.25*ACCI^T, 64..127 = cat_emb^T
// ---------------------------------------------------------------------------
__global__ __launch_bounds__(64) void build_it_kernel(
    const float* __restrict__ ACCI, const float* __restrict__ cat_emb,
    const int* __restrict__ item_cat, float* __restrict__ IT) {
  int m = blockIdx.x * 64 + threadIdx.x;
  if (m >= M_ITEMS) return;
  int cid = item_cat[m];
#pragma unroll 4
  for (int k = 0; k < DIM; ++k) {
    IT[k * M_ITEMS + m] = 0.25f * ACCI[m * DIM + k];
    IT[(DIM + k) * M_ITEMS + m] = cat_emb[cid * DIM + k];
  }
}

// ---------------------------------------------------------------------------
// gemm: out[b][m] = sum_{k<128} U2T[k][b] * IT[k][m]
// ---------------------------------------------------------------------------
#define GK 32
#define LDP 72
__global__ __launch_bounds__(256) void gemm_kernel(
    const float* __restrict__ U2T, const float* __restrict__ IT,
    float* __restrict__ out) {
  __shared__ float sU[GK][LDP];
  __shared__ float sI[GK][LDP];
  const int m0 = blockIdx.x * 64;
  const int b0 = blockIdx.y * 64;
  const int tid = threadIdx.x;
  const int tx = tid & 15;
  const int ty = tid >> 4;
  const bool full = (m0 + 64 <= M_ITEMS);

  float acc[4][4] = {};

  for (int k0 = 0; k0 < 2 * DIM; k0 += GK) {
    int linear = tid * 8;
    int kk = linear >> 6;
    int col = linear & 63;
    {
      const float* src = &U2T[(k0 + kk) * BATCH + b0 + col];
      *(float4*)&sU[kk][col] = *(const float4*)(src);
      *(float4*)&sU[kk][col + 4] = *(const float4*)(src + 4);
    }
    if (full) {
      const float* src = &IT[(k0 + kk) * M_ITEMS + m0 + col];
      *(float4*)&sI[kk][col] = *(const float4*)(src);
      *(float4*)&sI[kk][col + 4] = *(const float4*)(src + 4);
    } else {
#pragma unroll
      for (int j = 0; j < 8; ++j) {
        int m = m0 + col + j;
        sI[kk][col + j] = (m < M_ITEMS) ? IT[(k0 + kk) * M_ITEMS + m] : 0.f;
      }
    }
    __syncthreads();

#pragma unroll
    for (int k = 0; k < GK; ++k) {
      float4 uv = *(const float4*)&sU[k][ty * 4];
      float4 iv = *(const float4*)&sI[k][tx * 4];
      float ua[4] = {uv.x, uv.y, uv.z, uv.w};
      float ia[4] = {iv.x, iv.y, iv.z, iv.w};
#pragma unroll
      for (int bi = 0; bi < 4; ++bi)
#pragma unroll
        for (int mi = 0; mi < 4; ++mi)
          acc[bi][mi] = fmaf(ua[bi], ia[mi], acc[bi][mi]);
    }
    __syncthreads();
  }

#pragma unroll
  for (int bi = 0; bi < 4; ++bi) {
    int b = b0 + ty * 4 + bi;
    int m = m0 + tx * 4;
    if (full) {
      float4 v = make_float4(acc[bi][0], acc[bi][1], acc[bi][2], acc[bi][3]);
      *(float4*)&out[b * M_ITEMS + m] = v;
    } else {
#pragma unroll
      for (int mi = 0; mi < 4; ++mi)
        if (m + mi < M_ITEMS) out[b * M_ITEMS + m + mi] = acc[bi][mi];
    }
  }
}

// ---------------------------------------------------------------------------
// launch
// ---------------------------------------------------------------------------
extern "C" void kernel_launch(void* const* d_in, const int* in_sizes, int n_in,
                              void* d_out, int out_size, void* d_ws, size_t ws_size,
                              hipStream_t stream) {
  const float* user_emb   = (const float*)d_in[0];
  const float* item_emb   = (const float*)d_in[1];
  const float* cat_emb    = (const float*)d_in[2];
  const float* graph_vals = (const float*)d_in[3];
  const int*   graph_rows = (const int*)d_in[4];
  const int*   graph_cols = (const int*)d_in[5];
  const int*   top3       = (const int*)d_in[6];
  const int*   item_cat   = (const int*)d_in[7];
  const int*   users      = (const int*)d_in[8];
  const float* thetas     = (const float*)d_in[9];
  float* out = (float*)d_out;

  // workspace layout (4-byte words):
  // A(9.6M) | B(9.6M) | pairs(9.6M) | ACCI(3.2M) | UACC(64K) | cnt | rp |
  // cursor | bcur | bsum | boff
  float* A      = (float*)d_ws;
  float* B      = A + NE;
  int2*  pairs  = (int2*)(B + NE);
  float* ACCI   = (float*)(pairs + NNZ_CNT);
  float* UACC   = ACCI + NI;
  int*   cnt    = (int*)(UACC + BATCH * DIM);
  int*   rp     = cnt + (N_NODES + 1);
  int*   cursor = rp + (N_NODES + 1);
  int*   bcur   = cursor + N_NODES;
  int*   bsum   = bcur + NB;
  int*   boff   = bsum + NSB;
  // stage aliases B (dead until first spmm writes it)
  int2* stage = (int2*)B;
  // IT / U2T alias A (dead after layer 2)
  float* IT  = A;
  float* U2T = A + 2 * DIM * M_ITEMS;  // 6.4M offset, fits in A's 9.6M

  init_kernel<<<2048, 256, 0, stream>>>(user_emb, item_emb, A, ACCI);
  zero_kernel<<<256, 256, 0, stream>>>(cnt, N_NODES + 1);
  hist_kernel<<<2048, 256, 0, stream>>>(graph_rows, cnt);
  scan_sums_kernel<<<NSB, SCB, 0, stream>>>(cnt, bsum);
  scan_offsets_kernel<<<1, 256, 0, stream>>>(bsum, boff, rp);
  scan_write_kernel<<<NSB, SCB, 0, stream>>>(cnt, boff, rp, cursor);
  binit_kernel<<<1, 256, 0, stream>>>(rp, bcur);
  bucket_stage_kernel<<<NCHUNKS, 256, 0, stream>>>(graph_rows, graph_cols,
                                                   graph_vals, bcur, stage);
  bucket_scatter_kernel<<<NB, 512, 0, stream>>>(stage, rp, cursor, pairs);
  uacc_kernel<<<BATCH * DIM / 256, 256, 0, stream>>>(user_emb, users, UACC, 0);

  float* cur = A;
  float* nxt = B;
  for (int l = 0; l < 3; ++l) {
    spmm_csr_kernel<<<(N_NODES + 3) / 4, 256, 0, stream>>>(cur, nxt, ACCI, rp,
                                                           pairs);
    uacc_kernel<<<BATCH * DIM / 256, 256, 0, stream>>>(nxt, users, UACC, 1);
    float* t = cur; cur = nxt; nxt = t;
  }

  clock_kernel<<<BATCH, 64, 0, stream>>>(users, thetas, top3, cat_emb, UACC, U2T);
  build_it_kernel<<<(M_ITEMS + 63) / 64, 64, 0, stream>>>(ACCI, cat_emb,
                                                          item_cat, IT);
  dim3 ggrid((M_ITEMS + 63) / 64, BATCH / 64);
  gemm_kernel<<<ggrid, 256, 0, stream>>>(U2T, IT, out);
}

// Round 4
// 1127.902 us; speedup vs baseline: 2.2895x; 1.2009x over previous
//
#include <hip/hip_runtime.h>
#include <math.h>

#define N_USERS 100000
#define M_ITEMS 50000
#define N_NODES 150000
#define DIM 64
#define TIME_BINS 24
#define NNZ_CNT 4800000
#define BATCH 1024
#define NE (N_NODES * DIM)   // 9,600,000
#define NU (N_USERS * DIM)   // 6,400,000
#define NI (M_ITEMS * DIM)   // 3,200,000
#define TWO_PI 6.283185307179586f

// bucketed scatter params
#define BSHIFT 10
#define NB ((N_NODES + (1 << BSHIFT) - 1) >> BSHIFT)  // 147
#define CHUNK 4096
#define NCHUNKS ((NNZ_CNT + CHUNK - 1) / CHUNK)       // 1172

// ---------------------------------------------------------------------------
// init: A = concat(user_emb, item_emb); ACCI = item_emb (layer-0 term)
// ---------------------------------------------------------------------------
__global__ __launch_bounds__(256) void init_kernel(
    const float* __restrict__ user_emb, const float* __restrict__ item_emb,
    float* __restrict__ A, float* __restrict__ ACCI) {
  const int nA4 = NE / 4, nI4 = NI / 4, u4 = NU / 4;
  int stride = gridDim.x * blockDim.x;
  for (int i = blockIdx.x * blockDim.x + threadIdx.x; i < nA4 + nI4; i += stride) {
    if (i < nA4) {
      float4 v = (i < u4) ? ((const float4*)user_emb)[i]
                          : ((const float4*)item_emb)[i - u4];
      ((float4*)A)[i] = v;
    } else {
      ((float4*)ACCI)[i - nA4] = ((const float4*)item_emb)[i - nA4];
    }
  }
}

__global__ __launch_bounds__(256) void zero_kernel(int* __restrict__ p, int n) {
  int stride = gridDim.x * blockDim.x;
  for (int i = blockIdx.x * blockDim.x + threadIdx.x; i < n; i += stride)
    p[i] = 0;
}

// ---------------------------------------------------------------------------
// bucket histogram: LDS-aggregated counts of row>>BSHIFT (147 counters).
// Replaces the 150K-counter global hist whose lines ping-ponged across XCDs.
// ---------------------------------------------------------------------------
__global__ __launch_bounds__(256) void bhist_kernel(
    const int* __restrict__ rows, int* __restrict__ bcnt) {
  __shared__ int lh[NB];
  for (int i = threadIdx.x; i < NB; i += 256) lh[i] = 0;
  __syncthreads();
  int stride = gridDim.x * 256;
  for (int i = blockIdx.x * 256 + threadIdx.x; i < NNZ_CNT; i += stride)
    atomicAdd(&lh[rows[i] >> BSHIFT], 1);
  __syncthreads();
  for (int i = threadIdx.x; i < NB; i += 256) {
    int v = lh[i];
    if (v) atomicAdd(&bcnt[i], v);
  }
}

// scan the NB bucket counts -> bbase[NB+1] (exclusive), bcur (alloc cursors),
// and rp[N_NODES] = total
__global__ __launch_bounds__(256) void bscan_kernel(
    const int* __restrict__ bcnt, int* __restrict__ bbase,
    int* __restrict__ bcur, int* __restrict__ rp) {
  __shared__ int tmp[256];
  int t = threadIdx.x;
  int x = (t < NB) ? bcnt[t] : 0;
  tmp[t] = x;
  __syncthreads();
  for (int off = 1; off < 256; off <<= 1) {
    int y = (t >= off) ? tmp[t - off] : 0;
    __syncthreads();
    tmp[t] += y;
    __syncthreads();
  }
  if (t < NB) {
    int e = tmp[t] - x;
    bbase[t] = e;
    bcur[t] = e;
  }
  if (t == NB - 1) {
    bbase[NB] = tmp[t];
    rp[N_NODES] = tmp[t];
  }
}

// ---------------------------------------------------------------------------
// pass 1: bin (row,col,val) into NB row-buckets with block-local grouping so
// each bucket gets a contiguous ~28-item run per chunk (coalesced writes).
// item packed as ((row & 1023) << 18 | col, val_bits).
// ---------------------------------------------------------------------------
__global__ __launch_bounds__(256) void bucket_stage_kernel(
    const int* __restrict__ rows, const int* __restrict__ cols,
    const float* __restrict__ vals, int* __restrict__ bcur,
    int2* __restrict__ stage) {
  __shared__ int lhist[NB];
  __shared__ int loffs[NB];
  __shared__ int gbase[NB];
  __shared__ int tmp[256];
  __shared__ int2 sitems[CHUNK];
  __shared__ unsigned char sbkt[CHUNK];

  const int tid = threadIdx.x;
  const int chunk0 = blockIdx.x * CHUNK;
  int n = NNZ_CNT - chunk0;
  if (n > CHUNK) n = CHUNK;

  for (int i = tid; i < NB; i += 256) lhist[i] = 0;
  __syncthreads();

  int key[16], vbits[16], pr[16];
#pragma unroll
  for (int u = 0; u < 16; ++u) {
    int li = u * 256 + tid;
    if (li < n) {
      int i = chunk0 + li;
      int r = rows[i];
      int c = cols[i];
      float v = vals[i];
      int b = r >> BSHIFT;
      int rank = atomicAdd(&lhist[b], 1);
      key[u] = ((r & ((1 << BSHIFT) - 1)) << 18) | c;
      vbits[u] = __float_as_int(v);
      pr[u] = (b << 12) | rank;
    } else {
      pr[u] = -1;
    }
  }
  __syncthreads();

  // inclusive scan over NB (padded to 256)
  int x = (tid < NB) ? lhist[tid] : 0;
  tmp[tid] = x;
  __syncthreads();
  for (int off = 1; off < 256; off <<= 1) {
    int y = (tid >= off) ? tmp[tid - off] : 0;
    __syncthreads();
    tmp[tid] += y;
    __syncthreads();
  }
  if (tid < NB) {
    loffs[tid] = tmp[tid] - x;  // exclusive offset
    gbase[tid] = (x > 0) ? atomicAdd(&bcur[tid], x) : 0;
  }
  __syncthreads();

  // scatter to LDS grouped by bucket
#pragma unroll
  for (int u = 0; u < 16; ++u) {
    if (pr[u] >= 0) {
      int b = pr[u] >> 12;
      int rank = pr[u] & 4095;
      int p = loffs[b] + rank;
      sitems[p] = make_int2(key[u], vbits[u]);
      sbkt[p] = (unsigned char)b;
    }
  }
  __syncthreads();

  // coalesced run writes to global bucket windows
  for (int j = tid; j < n; j += 256) {
    int b = sbkt[j];
    int2 it = sitems[j];
    stage[gbase[b] + (j - loffs[b])] = it;
  }
}

// ---------------------------------------------------------------------------
// pass 2: one block per bucket. LDS row-hist (1024 counters) -> LDS scan ->
// coalesced rp write -> scatter with LDS cursors into the bucket's L2-local
// pairs window. Replaces global hist + 3-phase scan + global-atomic scatter.
// ---------------------------------------------------------------------------
__global__ __launch_bounds__(1024) void bucket_finalize_kernel(
    const int2* __restrict__ stage, const int* __restrict__ bbase,
    int* __restrict__ rp, int2* __restrict__ pairs) {
  __shared__ int lhist[1 << BSHIFT];
  __shared__ int lcur[1 << BSHIFT];
  __shared__ int ws[16];
  const int b = blockIdx.x;
  const int t = threadIdx.x;
  const int rbase = b << BSHIFT;
  const int wstart = bbase[b];
  const int wend = bbase[b + 1];

  lhist[t] = 0;
  __syncthreads();

  for (int j = wstart + t; j < wend; j += 1024)
    atomicAdd(&lhist[stage[j].x >> 18], 1);
  __syncthreads();

  // block-wide exclusive scan of lhist
  int x = lhist[t];
  int lane = t & 63, wid = t >> 6;
  int inc = x;
#pragma unroll
  for (int off = 1; off < 64; off <<= 1) {
    int y = __shfl_up(inc, off);
    if (lane >= off) inc += y;
  }
  if (lane == 63) ws[wid] = inc;
  __syncthreads();
  int wofs = 0;
  for (int w = 0; w < wid; ++w) wofs += ws[w];
  int excl = wstart + wofs + inc - x;
  lcur[t] = excl;
  if (rbase + t < N_NODES) rp[rbase + t] = excl;
  __syncthreads();

  for (int j = wstart + t; j < wend; j += 1024) {
    int2 it = stage[j];
    int lr = it.x >> 18;
    int c = it.x & 0x3FFFF;
    int pos = atomicAdd(&lcur[lr], 1);
    pairs[pos] = make_int2(c, it.y);
  }
}

// ---------------------------------------------------------------------------
// CSR SpMM: one wave per row, lane = dim. Lane-cooperative pair load +
// shuffle-broadcast + 8-deep unrolled gather batches.
// ---------------------------------------------------------------------------
__global__ __launch_bounds__(256) void spmm_csr_kernel(
    const float* __restrict__ ecur, float* __restrict__ enext,
    float* __restrict__ ACCI, const int* __restrict__ rp,
    const int2* __restrict__ pairs) {
  int r = blockIdx.x * 4 + (threadIdx.x >> 6);
  int lane = threadIdx.x & 63;
  if (r >= N_NODES) return;
  int start = rp[r];
  int end = rp[r + 1];
  float acc = 0.f;

  for (int jb = start; jb < end; jb += 64) {
    int n = end - jb;
    if (n > 64) n = 64;
    int jj = jb + lane;
    if (jj >= end) jj = end - 1;          // clamp: lanes >= n read a dup, unused
    int2 mp = pairs[jj];                  // one coalesced load covers the batch

    int k = 0;
    for (; k + 8 <= n; k += 8) {
      float v[8], g[8];
#pragma unroll
      for (int u = 0; u < 8; ++u) {
        int c = __shfl(mp.x, k + u);
        v[u] = __int_as_float(__shfl(mp.y, k + u));
        g[u] = ecur[c * DIM + lane];      // 8 independent gathers in flight
      }
#pragma unroll
      for (int u = 0; u < 8; ++u) acc = fmaf(v[u], g[u], acc);
    }
    if (k + 4 <= n) {
      float v[4], g[4];
#pragma unroll
      for (int u = 0; u < 4; ++u) {
        int c = __shfl(mp.x, k + u);
        v[u] = __int_as_float(__shfl(mp.y, k + u));
        g[u] = ecur[c * DIM + lane];
      }
#pragma unroll
      for (int u = 0; u < 4; ++u) acc = fmaf(v[u], g[u], acc);
      k += 4;
    }
    for (; k < n; ++k) {
      int c = __shfl(mp.x, k);
      float v = __int_as_float(__shfl(mp.y, k));
      acc = fmaf(v, ecur[c * DIM + lane], acc);
    }
  }

  enext[r * DIM + lane] = acc;
  if (r >= N_USERS) {
    int ir = r - N_USERS;
    ACCI[ir * DIM + lane] += acc;
  }
}

// gather batch-user rows of src into UACC (add=0: init, add=1: accumulate)
__global__ __launch_bounds__(256) void uacc_kernel(
    const float* __restrict__ src, const int* __restrict__ users,
    float* __restrict__ UACC, int add) {
  int idx = blockIdx.x * 256 + threadIdx.x;  // BATCH*64 total
  int b = idx >> 6, d = idx & 63;
  int u = users[b];
  float v = src[u * DIM + d];
  if (add) UACC[idx] += v; else UACC[idx] = v;
}

// ---------------------------------------------------------------------------
// clock: U2T[d][b] = 0.25*UACC[b][d]; U2T[64+d][b] = 0.5 * v_clock[b][d]
// ---------------------------------------------------------------------------
__global__ __launch_bounds__(64) void clock_kernel(
    const int* __restrict__ users, const float* __restrict__ thetas,
    const int* __restrict__ top3, const float* __restrict__ cat_emb,
    const float* __restrict__ UACC, float* __restrict__ U2T) {
  int b = blockIdx.x;
  int d = threadIdx.x;
  int u = users[b];
  float cur = thetas[b] * ((float)TIME_BINS / TWO_PI);

  float w[TIME_BINS];
  float S = 0.f;
#pragma unroll
  for (int h = 0; h < TIME_BINS; ++h) {
    float diff = fabsf(cur - (float)h);
    float delta = fminf(diff, (float)TIME_BINS - diff);
    float wh = expf(-0.5f * delta * delta);
    w[h] = wh;
    S += wh;
  }
  float inv = 1.f / (S + 1e-8f);

  float v = 0.f;
#pragma unroll
  for (int h = 0; h < TIME_BINS; ++h) {
    int base = u * (TIME_BINS * 3) + h * 3;
    int i0 = top3[base + 0];
    int i1 = top3[base + 1];
    int i2 = top3[base + 2];
    float he = (cat_emb[i0 * DIM + d] + cat_emb[i1 * DIM + d] +
                cat_emb[i2 * DIM + d]) * (1.f / 3.f);
    v += w[h] * he;
  }
  U2T[d * BATCH + b] = 0.25f * UACC[b * DIM + d];
  U2T[(DIM + d) * BATCH + b] = 0.5f * v * inv;
}

// ---------------------------------------------------------------------------
// build item matrix IT[128][M]: rows 0..63 = 0.25*ACCI^T, 64..127 = cat_emb^T
// ---------------------------------------------------------------------------
__global__ __launch_bounds__(64) void build_it_kernel(
    const float* __restrict__ ACCI, const float* __restrict__ cat_emb,
    const int* __restrict__ item_cat, float* __restrict__ IT) {
  int m = blockIdx.x * 64 + threadIdx.x;
  if (m >= M_ITEMS) return;
  int cid = item_cat[m];
#pragma unroll 4
  for (int k = 0; k < DIM; ++k) {
    IT[k * M_ITEMS + m] = 0.25f * ACCI[m * DIM + k];
    IT[(DIM + k) * M_ITEMS + m] = cat_emb[cid * DIM + k];
  }
}

// ---------------------------------------------------------------------------
// gemm: out[b][m] = sum_{k<128} U2T[k][b] * IT[k][m]
// 128x128 tile, 256 threads, 8x8 microtile (split 4+4 to keep LDS reads
// 2-way-or-better). Halves ds_read wave-instrs per FMA vs the 64x64/4x4.
// ---------------------------------------------------------------------------
#define GK 32
#define GM 128
#define GB 128
#define LDW 132
__global__ __launch_bounds__(256) void gemm_kernel(
    const float* __restrict__ U2T, const float* __restrict__ IT,
    float* __restrict__ out) {
  __shared__ float sU[GK][LDW];
  __shared__ float sI[GK][LDW];
  const int m0 = blockIdx.x * GM;
  const int b0 = blockIdx.y * GB;
  const int tid = threadIdx.x;
  const int tx = tid & 15;   // m group
  const int ty = tid >> 4;   // b group
  const bool full = (m0 + GM <= M_ITEMS);

  float acc[8][8] = {};  // [b: bh*4+i][m: mh*4+j]

  for (int k0 = 0; k0 < 2 * DIM; k0 += GK) {
    // stage 32x128 of each matrix: 1024 float4, 4 per thread, lane-coalesced
#pragma unroll
    for (int i = 0; i < 4; ++i) {
      int f = i * 256 + tid;       // float4 index 0..1023
      int kk = f >> 5;             // row (32 float4 per row)
      int c4 = (f & 31) * 4;       // float col 0..124
      *(float4*)&sU[kk][c4] = *(const float4*)&U2T[(k0 + kk) * BATCH + b0 + c4];
      if (full || (m0 + c4 + 3 < M_ITEMS)) {
        *(float4*)&sI[kk][c4] = *(const float4*)&IT[(k0 + kk) * M_ITEMS + m0 + c4];
      } else {
        *(float4*)&sI[kk][c4] = make_float4(0.f, 0.f, 0.f, 0.f);
      }
    }
    __syncthreads();

#pragma unroll
    for (int k = 0; k < GK; ++k) {
      float4 u0 = *(const float4*)&sU[k][ty * 4];
      float4 u1 = *(const float4*)&sU[k][64 + ty * 4];
      float4 i0 = *(const float4*)&sI[k][tx * 4];
      float4 i1 = *(const float4*)&sI[k][64 + tx * 4];
      float ub[8] = {u0.x, u0.y, u0.z, u0.w, u1.x, u1.y, u1.z, u1.w};
      float im[8] = {i0.x, i0.y, i0.z, i0.w, i1.x, i1.y, i1.z, i1.w};
#pragma unroll
      for (int bi = 0; bi < 8; ++bi)
#pragma unroll
        for (int mj = 0; mj < 8; ++mj)
          acc[bi][mj] = fmaf(ub[bi], im[mj], acc[bi][mj]);
    }
    __syncthreads();
  }

#pragma unroll
  for (int bh = 0; bh < 2; ++bh) {
#pragma unroll
    for (int i = 0; i < 4; ++i) {
      int b = b0 + bh * 64 + ty * 4 + i;
#pragma unroll
      for (int mh = 0; mh < 2; ++mh) {
        int m = m0 + mh * 64 + tx * 4;
        if (m + 3 < M_ITEMS) {
          float4 v = make_float4(acc[bh * 4 + i][mh * 4 + 0],
                                 acc[bh * 4 + i][mh * 4 + 1],
                                 acc[bh * 4 + i][mh * 4 + 2],
                                 acc[bh * 4 + i][mh * 4 + 3]);
          *(float4*)&out[b * M_ITEMS + m] = v;
        }
      }
    }
  }
}

// ---------------------------------------------------------------------------
// launch
// ---------------------------------------------------------------------------
extern "C" void kernel_launch(void* const* d_in, const int* in_sizes, int n_in,
                              void* d_out, int out_size, void* d_ws, size_t ws_size,
                              hipStream_t stream) {
  const float* user_emb   = (const float*)d_in[0];
  const float* item_emb   = (const float*)d_in[1];
  const float* cat_emb    = (const float*)d_in[2];
  const float* graph_vals = (const float*)d_in[3];
  const int*   graph_rows = (const int*)d_in[4];
  const int*   graph_cols = (const int*)d_in[5];
  const int*   top3       = (const int*)d_in[6];
  const int*   item_cat   = (const int*)d_in[7];
  const int*   users      = (const int*)d_in[8];
  const float* thetas     = (const float*)d_in[9];
  float* out = (float*)d_out;

  // workspace layout (4-byte words):
  // A(9.6M) | B(9.6M) | pairs(9.6M) | ACCI(3.2M) | UACC(64K) | rp | bcnt |
  // bbase | bcur
  float* A      = (float*)d_ws;
  float* B      = A + NE;
  int2*  pairs  = (int2*)(B + NE);
  float* ACCI   = (float*)(pairs + NNZ_CNT);
  float* UACC   = ACCI + NI;
  int*   rp     = (int*)(UACC + BATCH * DIM);
  int*   bcnt   = rp + (N_NODES + 1);
  int*   bbase  = bcnt + NB;
  int*   bcur   = bbase + (NB + 1);
  // stage aliases B (dead until first spmm writes it)
  int2* stage = (int2*)B;
  // IT / U2T alias A (dead after layer 2)
  float* IT  = A;
  float* U2T = A + 2 * DIM * M_ITEMS;  // 6.4M offset, fits in A's 9.6M

  init_kernel<<<2048, 256, 0, stream>>>(user_emb, item_emb, A, ACCI);
  zero_kernel<<<1, 256, 0, stream>>>(bcnt, NB);
  bhist_kernel<<<1024, 256, 0, stream>>>(graph_rows, bcnt);
  bscan_kernel<<<1, 256, 0, stream>>>(bcnt, bbase, bcur, rp);
  bucket_stage_kernel<<<NCHUNKS, 256, 0, stream>>>(graph_rows, graph_cols,
                                                   graph_vals, bcur, stage);
  bucket_finalize_kernel<<<NB, 1024, 0, stream>>>(stage, bbase, rp, pairs);
  uacc_kernel<<<BATCH * DIM / 256, 256, 0, stream>>>(user_emb, users, UACC, 0);

  float* cur = A;
  float* nxt = B;
  for (int l = 0; l < 3; ++l) {
    spmm_csr_kernel<<<(N_NODES + 3) / 4, 256, 0, stream>>>(cur, nxt, ACCI, rp,
                                                           pairs);
    uacc_kernel<<<BATCH * DIM / 256, 256, 0, stream>>>(nxt, users, UACC, 1);
    float* t = cur; cur = nxt; nxt = t;
  }

  clock_kernel<<<BATCH, 64, 0, stream>>>(users, thetas, top3, cat_emb, UACC, U2T);
  build_it_kernel<<<(M_ITEMS + 63) / 64, 64, 0, stream>>>(ACCI, cat_emb,
                                                          item_cat, IT);
  dim3 ggrid((M_ITEMS + GM - 1) / GM, BATCH / GB);
  gemm_kernel<<<ggrid, 256, 0, stream>>>(U2T, IT, out);
}